// Round 9
// baseline (437.507 us; speedup 1.0000x reference)
//
#include <hip/hip_runtime.h>

#define N_ 32
#define C_ 128
#define K_ 64
#define S_ 16384
#define NBPB 16               // blocks per image (512 total = 2/CU exactly, 1 round)
#define NBLK (N_*NBPB)        // 512
#define SPB 32                // 32-s slabs per block (16384 / 16 / 32)
#define WS 128                // sW stride (halfs), XOR-swizzled
#define EPS 1e-12f

typedef __attribute__((ext_vector_type(8))) _Float16 half8;
typedef __attribute__((ext_vector_type(2))) _Float16 half2v;
typedef __attribute__((ext_vector_type(4))) float floatx4;
typedef __attribute__((ext_vector_type(4))) int intx4;

__device__ __forceinline__ int swz(int row, int c) {
  return (((c >> 4) ^ (row & 7)) << 4) | (c & 15);
}

// Sum over the 16-lane DPP row via row_ror rotate-reduce — pure VALU, no LDS pipe.
__device__ __forceinline__ float rowsum16(float v) {
  int b;
  b = __builtin_amdgcn_mov_dpp(__builtin_bit_cast(int, v), 0x128, 0xF, 0xF, true);
  v += __builtin_bit_cast(float, b);   // + ror8
  b = __builtin_amdgcn_mov_dpp(__builtin_bit_cast(int, v), 0x124, 0xF, 0xF, true);
  v += __builtin_bit_cast(float, b);   // + ror4
  b = __builtin_amdgcn_mov_dpp(__builtin_bit_cast(int, v), 0x122, 0xF, 0xF, true);
  v += __builtin_bit_cast(float, b);   // + ror2
  b = __builtin_amdgcn_mov_dpp(__builtin_bit_cast(int, v), 0x121, 0xF, 0xF, true);
  v += __builtin_bit_cast(float, b);   // + ror1 — every lane holds row total
  return v;
}

// ---------------------------------------------------------------------------
// Wave-autonomous NetVLAD main kernel: ZERO barriers in the main loop.
// Each wave independently, per 32-s slab:
//   GEMM1: logits = mfma(xA-gather, W-from-LDS) for ALL 64 kc (4x redundant
//          across the block's 4 waves — MFMA pipe was 4% utilized, free)
//   softmax in-register (kt in-lane, lm via DPP rotate-reduce)
//   P regroup: fp16-pack + one __shfl gather/word (quad s-regroup, in-wave)
//   GEMM2: acc += mfma(xB, P) for this wave's own 32-c quarter
// x is read once: xA gather = dense 64B segments, full 128B lines per slab.
// LDS: sW 16KB + 37.9KB pad = 54272B > 53.3KB => 2 blocks/CU, which keeps the
// gfx950 allocator off the 64-VGPR occupancy clamp (R5/R6 spill storms).
// ---------------------------------------------------------------------------
template <bool SLAB>
__global__ __launch_bounds__(256, 2) void vlad_main(
    const float* __restrict__ x, const float* __restrict__ w,
    float* __restrict__ vlad_out, float* __restrict__ asum_out) {
  __shared__ _Float16 sW[K_ * WS];   // 16384 B
  __shared__ float sPad[9472];       // 37888 B pad (never touched at runtime)

  const int tid = threadIdx.x;
  const int lane = tid & 63;
  const int wv = tid >> 6;
  const int lm = lane & 15;
  const int q = lane >> 4;

  const int bid = blockIdx.x;
  const int n = bid >> 4;            // bid / NBPB
  const int bj = bid & 15;           // bid % NBPB

  // W -> LDS once (read-only afterwards; the ONLY __syncthreads in the kernel)
  for (int idx = tid; idx < K_ * C_; idx += 256) {
    int kc = idx >> 7, c = idx & 127;
    sW[kc * WS + swz(kc, c)] = (_Float16)w[idx];
  }
  if (w[0] > 1e30f) sPad[tid] = w[0];  // keep pad alive; never true for real data
  __syncthreads();

  floatx4 acc[2][4];                 // [ci][kt]: vlad[kc=kt*16+lm][c=wv*32+ci*16+q*4+r]
#pragma unroll
  for (int ci = 0; ci < 2; ++ci)
#pragma unroll
    for (int kt = 0; kt < 4; ++kt) acc[ci][kt] = (floatx4){0.f, 0.f, 0.f, 0.f};
  float accA[4] = {0.f, 0.f, 0.f, 0.f};

  const float* xn = x + (size_t)n * C_ * S_;
  // xA gather base: element (c = ks*32 + q*8 + j, s = s0 + sg*16 + lm)
  const float* pA = xn + (size_t)(q * 8) * S_ + lm;
  // xB base: element (c = wv*32 + ci*16 + lm, s = s0 + q*8 + [0..7])
  const float* pB = xn + (size_t)(wv * 32 + lm) * S_ + q * 8;

  for (int i = 0; i < SPB; ++i) {
    const int s0 = (bj * SPB + i) * 32;
    const float* pAs = pA + s0;

    // ---- issue loads: xA slots ks0,ks1 (32 dwords) + xB (4 float4) ----
    float xa[2][2][8];   // [ks&1][sg][j]
#pragma unroll
    for (int ks = 0; ks < 2; ++ks)
#pragma unroll
      for (int sg = 0; sg < 2; ++sg)
#pragma unroll
        for (int j = 0; j < 8; ++j)
          xa[ks][sg][j] = pAs[(size_t)(ks * 32 + j) * S_ + sg * 16];

    float4 xb[2][2];
#pragma unroll
    for (int ci = 0; ci < 2; ++ci) {
      const float* p = pB + (size_t)(ci * 16) * S_ + s0;
      xb[ci][0] = *(const float4*)p;
      xb[ci][1] = *(const float4*)(p + 4);
    }

    // ---- GEMM1: D[sg][kt] = logits[s = sg*16+q*4+r][kc = kt*16+lm] ----
    floatx4 D[2][4];
#pragma unroll
    for (int sg = 0; sg < 2; ++sg)
#pragma unroll
      for (int kt = 0; kt < 4; ++kt) D[sg][kt] = (floatx4){0.f, 0.f, 0.f, 0.f};

#pragma unroll
    for (int ks = 0; ks < 4; ++ks) {
      half8 Wf[4];
#pragma unroll
      for (int kt = 0; kt < 4; ++kt) {
        const int krow = kt * 16 + lm;
        Wf[kt] = *(const half8*)&sW[krow * WS + swz(krow, ks * 32 + q * 8)];
      }
      half8 Af[2];
#pragma unroll
      for (int sg = 0; sg < 2; ++sg)
#pragma unroll
        for (int j = 0; j < 8; ++j)
          Af[sg][j] = (_Float16)xa[ks & 1][sg][j];
      // refill the freed slot with ks+2 (in-slab software pipeline)
      if (ks < 2) {
#pragma unroll
        for (int sg = 0; sg < 2; ++sg)
#pragma unroll
          for (int j = 0; j < 8; ++j)
            xa[ks & 1][sg][j] = pAs[(size_t)((ks + 2) * 32 + j) * S_ + sg * 16];
      }
#pragma unroll
      for (int sg = 0; sg < 2; ++sg)
#pragma unroll
        for (int kt = 0; kt < 4; ++kt)
          D[sg][kt] = __builtin_amdgcn_mfma_f32_16x16x32_f16(Af[sg], Wf[kt], D[sg][kt], 0, 0, 0);
    }

    // ---- softmax over 64 kc per s-row (kt in-lane x4, lm via DPP rows) ----
    // no max-sub: logits ~ N(0,1.28), |logit| <~ 7, fp32 exp cannot overflow
#pragma unroll
    for (int sg = 0; sg < 2; ++sg)
#pragma unroll
      for (int r = 0; r < 4; ++r) {
        float e0 = __expf(D[sg][0][r]), e1 = __expf(D[sg][1][r]),
              e2 = __expf(D[sg][2][r]), e3 = __expf(D[sg][3][r]);
        float inv = 1.f / rowsum16(e0 + e1 + e2 + e3);
        D[sg][0][r] = e0 * inv; D[sg][1][r] = e1 * inv;
        D[sg][2][r] = e2 * inv; D[sg][3][r] = e3 * inv;
      }
    if (wv == 0) {   // waves compute identical P; only wave 0 tallies asum
#pragma unroll
      for (int kt = 0; kt < 4; ++kt)
        accA[kt] += D[0][kt][0] + D[0][kt][1] + D[0][kt][2] + D[0][kt][3]
                  + D[1][kt][0] + D[1][kt][1] + D[1][kt][2] + D[1][kt][3];
    }

    // ---- cvt xB (flight complete by now) ----
    half8 xbh[2];
#pragma unroll
    for (int ci = 0; ci < 2; ++ci) {
      xbh[ci][0] = (_Float16)xb[ci][0].x; xbh[ci][1] = (_Float16)xb[ci][0].y;
      xbh[ci][2] = (_Float16)xb[ci][0].z; xbh[ci][3] = (_Float16)xb[ci][0].w;
      xbh[ci][4] = (_Float16)xb[ci][1].x; xbh[ci][5] = (_Float16)xb[ci][1].y;
      xbh[ci][6] = (_Float16)xb[ci][1].z; xbh[ci][7] = (_Float16)xb[ci][1].w;
    }

    // ---- P pack + in-wave quad regroup -> GEMM2 B-frags ----
    // source: lane(lm,qs) holds P[s=sg*16+qs*4+r][kc=kt*16+lm]
    // target: lane(lm,q) reg rr holds halfs j=2rr,2rr+1 of P[s=q*8+j][kc=kt*16+lm]
    //   sg = q>>1 ; src lane = ((q&1)*2 + (rr>>1))*16 + lm  (verified 4 elems)
    half8 Pb[4];
    const int srcBase = ((lane >> 4) & 1) * 32 + lm;
#pragma unroll
    for (int kt = 0; kt < 4; ++kt) {
      int u0[2], u1[2];
#pragma unroll
      for (int rp = 0; rp < 2; ++rp) {
        half2v h0 = {(_Float16)D[0][kt][2 * rp], (_Float16)D[0][kt][2 * rp + 1]};
        half2v h1 = {(_Float16)D[1][kt][2 * rp], (_Float16)D[1][kt][2 * rp + 1]};
        u0[rp] = __builtin_bit_cast(int, h0);
        u1[rp] = __builtin_bit_cast(int, h1);
      }
      int wd[4];
#pragma unroll
      for (int rr = 0; rr < 4; ++rr) {
        const int src = srcBase + (rr >> 1) * 16;
        const int a0 = __shfl(u0[rr & 1], src);
        const int a1 = __shfl(u1[rr & 1], src);
        wd[rr] = (lane < 32) ? a0 : a1;
      }
      intx4 wq = {wd[0], wd[1], wd[2], wd[3]};
      Pb[kt] = __builtin_bit_cast(half8, wq);
    }

    // ---- GEMM2: acc[ci][kt] += mfma(A = x[c][s], B = P[s][kc]) ----
#pragma unroll
    for (int ci = 0; ci < 2; ++ci)
#pragma unroll
      for (int kt = 0; kt < 4; ++kt)
        acc[ci][kt] = __builtin_amdgcn_mfma_f32_16x16x32_f16(xbh[ci], Pb[kt], acc[ci][kt], 0, 0, 0);
  }

  // ---- epilogue: direct slab write (waves own disjoint c-quarters) ----
  if (SLAB) {
    float* vb = vlad_out + (size_t)bid * (K_ * C_);
#pragma unroll
    for (int ci = 0; ci < 2; ++ci)
#pragma unroll
      for (int kt = 0; kt < 4; ++kt)
        *(floatx4*)&vb[(size_t)(kt * 16 + lm) * C_ + wv * 32 + ci * 16 + q * 4] = acc[ci][kt];
  } else {
    float* vb = vlad_out + (size_t)n * (K_ * C_);
#pragma unroll
    for (int ci = 0; ci < 2; ++ci)
#pragma unroll
      for (int kt = 0; kt < 4; ++kt)
#pragma unroll
        for (int r = 0; r < 4; ++r)
          atomicAdd(vb + (size_t)(kt * 16 + lm) * C_ + wv * 32 + ci * 16 + q * 4 + r,
                    acc[ci][kt][r]);
  }
  if (wv == 0) {
#pragma unroll
    for (int kt = 0; kt < 4; ++kt) {
      float v = accA[kt];
      v += __shfl_xor(v, 16);
      v += __shfl_xor(v, 32);
      if (lane < 16) {
        if (SLAB) asum_out[bid * K_ + kt * 16 + lane] = v;
        else atomicAdd(asum_out + n * K_ + kt * 16 + lane, v);
      }
    }
  }
}

// ---------------------------------------------------------------------------
// Kernel 2: reduce slabs, subtract asum*centroid, intra-normalize, gnorm
// ---------------------------------------------------------------------------
template <bool SLAB>
__global__ __launch_bounds__(128) void vlad_intra(
    const float* __restrict__ vlad_in, const float* __restrict__ asum_in,
    const float* __restrict__ cent, float* __restrict__ vlad_norm,
    float* __restrict__ gnorm) {
  const int bid = blockIdx.x;
  const int n = bid >> 6, k = bid & 63;
  const int c = threadIdx.x;

  float v, a;
  if (SLAB) {
    v = 0.f; a = 0.f;
#pragma unroll 4
    for (int ch = 0; ch < NBPB; ++ch) {
      v += vlad_in[((size_t)(n * NBPB + ch) * K_ + k) * C_ + c];
      a += asum_in[(n * NBPB + ch) * K_ + k];
    }
  } else {
    v = vlad_in[((size_t)(n * K_ + k)) * C_ + c];
    a = asum_in[n * K_ + k];
  }
  v -= a * cent[k * C_ + c];

  float ss = v * v;
  ss += __shfl_xor(ss, 1);  ss += __shfl_xor(ss, 2);  ss += __shfl_xor(ss, 4);
  ss += __shfl_xor(ss, 8);  ss += __shfl_xor(ss, 16); ss += __shfl_xor(ss, 32);
  __shared__ float red[2];
  if ((threadIdx.x & 63) == 0) red[threadIdx.x >> 6] = ss;
  __syncthreads();
  float total = red[0] + red[1];
  float nrm = fmaxf(sqrtf(total), EPS);
  vlad_norm[((size_t)(n * K_ + k)) * C_ + c] = v / nrm;
  if (threadIdx.x == 0) atomicAdd(gnorm + n, total / (nrm * nrm));
}

// ---------------------------------------------------------------------------
// Kernel 3: global L2 normalize per n
// ---------------------------------------------------------------------------
__global__ __launch_bounds__(256) void vlad_final(
    const float* __restrict__ vlad_norm, const float* __restrict__ gnorm,
    float* __restrict__ out) {
  const int idx = blockIdx.x * 256 + threadIdx.x;
  if (idx >= N_ * K_ * C_) return;
  float g = gnorm[idx >> 13];
  out[idx] = vlad_norm[idx] / fmaxf(sqrtf(g), EPS);
}

extern "C" void kernel_launch(void* const* d_in, const int* in_sizes, int n_in,
                              void* d_out, int out_size, void* d_ws, size_t ws_size,
                              hipStream_t stream) {
  const float* x    = (const float*)d_in[0];
  const float* w    = (const float*)d_in[1];
  const float* cent = (const float*)d_in[2];
  float* out = (float*)d_out;

  const size_t slab_f = (size_t)NBLK * K_ * C_;    // 4,194,304 floats (16.8 MB)
  const size_t asum_f = (size_t)NBLK * K_;         // 32,768
  const size_t norm_f = (size_t)N_ * K_ * C_;      // 262,144
  const size_t need = (slab_f + asum_f + norm_f + N_) * sizeof(float);

  if (ws_size >= need) {
    float* slab  = (float*)d_ws;
    float* asums = slab + slab_f;
    float* vnorm = asums + asum_f;
    float* gnorm = vnorm + norm_f;
    hipMemsetAsync(gnorm, 0, N_ * sizeof(float), stream);
    vlad_main<true><<<dim3(NBLK), dim3(256), 0, stream>>>(x, w, slab, asums);
    vlad_intra<true><<<dim3(N_ * K_), dim3(128), 0, stream>>>(slab, asums, cent, vnorm, gnorm);
    vlad_final<<<dim3((N_ * K_ * C_ + 255) / 256), dim3(256), 0, stream>>>(vnorm, gnorm, out);
  } else {
    float* vlad_acc = (float*)d_ws;
    float* asum_g   = vlad_acc + norm_f;
    float* gnorm    = asum_g + N_ * K_;
    hipMemsetAsync(d_ws, 0, (norm_f + N_ * K_ + N_) * sizeof(float), stream);
    vlad_main<false><<<dim3(NBLK), dim3(256), 0, stream>>>(x, w, vlad_acc, asum_g);
    vlad_intra<false><<<dim3(N_ * K_), dim3(128), 0, stream>>>(vlad_acc, asum_g, cent, vlad_acc, gnorm);
    vlad_final<<<dim3((N_ * K_ * C_ + 255) / 256), dim3(256), 0, stream>>>(vlad_acc, gnorm, out);
  }
}